// Round 9
// baseline (652.130 us; speedup 1.0000x reference)
//
#include <hip/hip_runtime.h>

#define N_NODES 100000
#define N_EDGES 1600000
#define IN_C 128
#define HID_C 128
#define OUT_C 64

#define SH 8                 // bucket = dst >> 8 (256 nodes/bucket)
#define NBKT 391             // ceil(100000/256)
#define CAP 4608             // bucket capacity: mean 4096 + 8 sigma
#define EPB 4096             // edges per block in phase A
#define EPT 16               // EPB / 256

typedef __attribute__((ext_vector_type(8))) short bf16x8;
typedef __attribute__((ext_vector_type(4))) float f32x4;

// ---- bf16 helpers ----
static __device__ __forceinline__ unsigned f2bf(float f) {
  union { float f; unsigned u; } v; v.f = f;
  unsigned r = v.u + 0x7fffu + ((v.u >> 16) & 1u);
  return r >> 16;
}
static __device__ __forceinline__ float bf2f(unsigned hu) {
  union { unsigned u; float f; } v; v.u = hu << 16; return v.f;
}
static __device__ __forceinline__ float bflo(unsigned u) {
  union { unsigned u; float f; } v; v.u = u << 16; return v.f;
}
static __device__ __forceinline__ float bfhi(unsigned u) {
  union { unsigned u; float f; } v; v.u = u & 0xffff0000u; return v.f;
}

// ---------------- phase A: LDS-reorder radix partition by dst-bucket ----------------

__global__ __launch_bounds__(256) void k_partA(const int* __restrict__ src,
                                               const int* __restrict__ dst,
                                               int* __restrict__ bcnt,
                                               unsigned* __restrict__ tmp, int e) {
  __shared__ unsigned stage[EPB];        // 16 KB
  __shared__ unsigned short bid[EPB];    // 8 KB
  __shared__ int hist[NBKT];
  __shared__ int lstart[NBKT];
  __shared__ int base[NBKT];
  __shared__ int ps[256];
  const int t = threadIdx.x;
  const int e0 = blockIdx.x * EPB;
  const int m = (e0 + EPB < e ? EPB : e - e0);

  for (int i = t; i < NBKT; i += 256) hist[i] = 0;
  __syncthreads();

  int rsrc[EPT], rdst[EPT];
#pragma unroll
  for (int i = 0; i < EPT; ++i) {
    int idx = e0 + i * 256 + t;
    if (idx < e) {
      rsrc[i] = src[idx];
      rdst[i] = dst[idx];
      atomicAdd(&hist[rdst[i] >> SH], 1);
    }
  }
  __syncthreads();

  int a0 = (2 * t < NBKT) ? hist[2 * t] : 0;
  int a1 = (2 * t + 1 < NBKT) ? hist[2 * t + 1] : 0;
  ps[t] = a0 + a1;
  __syncthreads();
  for (int off = 1; off < 256; off <<= 1) {
    int add = (t >= off) ? ps[t - off] : 0;
    __syncthreads();
    ps[t] += add;
    __syncthreads();
  }
  int ex = ps[t] - (a0 + a1);
  if (2 * t < NBKT) lstart[2 * t] = ex;
  if (2 * t + 1 < NBKT) lstart[2 * t + 1] = ex + a0;

  for (int i = t; i < NBKT; i += 256) {
    int h = hist[i];
    base[i] = h ? atomicAdd(&bcnt[i], h) : 0;
    hist[i] = 0;
  }
  __syncthreads();

#pragma unroll
  for (int i = 0; i < EPT; ++i) {
    int idx = e0 + i * 256 + t;
    if (idx < e) {
      int d = rdst[i];
      int b = d >> SH;
      int pos = lstart[b] + atomicAdd(&hist[b], 1);
      stage[pos] = (unsigned)rsrc[i] | ((unsigned)(d & 255) << 17);
      bid[pos] = (unsigned short)b;
    }
  }
  __syncthreads();

  for (int pos = t; pos < m; pos += 256) {
    int b = bid[pos];
    int slot = base[b] + (pos - lstart[b]);
    if (slot < CAP)  // 8-sigma safety clamp
      tmp[(size_t)b * CAP + slot] = stage[pos];
  }
}

// fused per-bucket degree count + block scan + dis
__global__ __launch_bounds__(256) void k_cnt_scan(const unsigned* __restrict__ tmp,
                                                  const int* __restrict__ bcnt,
                                                  int* __restrict__ rowptr,
                                                  int* __restrict__ bsums,
                                                  float* __restrict__ dis, int n) {
  __shared__ int h[256];
  __shared__ int s[256];
  const int b = blockIdx.x, t = threadIdx.x;
  h[t] = 0;
  __syncthreads();
  int m = bcnt[b];
  if (m > CAP) m = CAP;
  for (int j = t; j < m; j += 256)
    atomicAdd(&h[tmp[(size_t)b * CAP + j] >> 17], 1);
  __syncthreads();
  const int node = (b << SH) + t;
  int v = (node < n) ? h[t] : 0;
  if (node < n) dis[node] = rsqrtf((float)(v + 1));
  s[t] = v;
  __syncthreads();
  for (int off = 1; off < 256; off <<= 1) {
    int add = (t >= off) ? s[t - off] : 0;
    __syncthreads();
    s[t] += add;
    __syncthreads();
  }
  if (node < n) rowptr[node] = s[t] - v;
  if (t == 255) bsums[b] = s[255];
}

__global__ void k_scan_sums(int* __restrict__ bsums, int nb) {
  __shared__ int s[512];
  int t = threadIdx.x;
  int v = (t < nb) ? bsums[t] : 0;
  s[t] = v;
  __syncthreads();
  for (int off = 1; off < 512; off <<= 1) {
    int add = (t >= off) ? s[t - off] : 0;
    __syncthreads();
    s[t] += add;
    __syncthreads();
  }
  if (t < nb) bsums[t] = s[t] - v;
}

__global__ void k_add_off(int* __restrict__ rowptr, const int* __restrict__ bsums,
                          int n, int e) {
  int i = blockIdx.x * blockDim.x + threadIdx.x;
  if (i < n) rowptr[i] += bsums[i >> 8];
  else if (i == n) rowptr[n] = e;
}

// phase B: bucket-local scatter to exact CSR slots (LDS cursors)
__global__ __launch_bounds__(512) void k_partB(const unsigned* __restrict__ tmp,
                                               const int* __restrict__ bcnt,
                                               const int* __restrict__ rowptr,
                                               int* __restrict__ col, int n) {
  __shared__ int cur[256];
  const int b = blockIdx.x;
  const int t = threadIdx.x;
  if (t < 256) {
    const int node = (b << SH) + t;
    cur[t] = (node < n) ? rowptr[node] : 0;
  }
  __syncthreads();
  int m = bcnt[b];
  if (m > CAP) m = CAP;
  for (int j = t; j < m; j += 512) {
    unsigned v = tmp[(size_t)b * CAP + j];
    int pos = atomicAdd(&cur[v >> 17], 1);
    col[pos] = (int)(v & 0x1FFFFu);
  }
}

// ---------------- weight prep: transpose + split-bf16 (W = hi + lo) ----------------

__global__ void k_prepW(const float* __restrict__ W1, const float* __restrict__ W2,
                        unsigned short* __restrict__ W1h, unsigned short* __restrict__ W1l,
                        unsigned short* __restrict__ W2h, unsigned short* __restrict__ W2l) {
  int i = blockIdx.x * blockDim.x + threadIdx.x;
  if (i < IN_C * HID_C) {
    int k = i >> 7, c = i & 127;
    float w = W1[i];
    unsigned hi = f2bf(w);
    W1h[c * 128 + k] = (unsigned short)hi;
    W1l[c * 128 + k] = (unsigned short)f2bf(w - bf2f(hi));
  }
  int j = i - IN_C * HID_C;
  if (j >= 0 && j < HID_C * OUT_C) {
    int k = j >> 6, c = j & 63;
    float w = W2[j];
    unsigned hi = f2bf(w);
    W2h[c * 128 + k] = (unsigned short)hi;
    W2l[c * 128 + k] = (unsigned short)f2bf(w - bf2f(hi));
  }
}

// ---------------- MFMA GEMM layer 1: Hb[group][node][16ch] = bf16((X@W1)*dis) ----------------

__global__ __launch_bounds__(256) void k_mfma1(const float* __restrict__ X,
                                               const unsigned short* __restrict__ Wh,
                                               const unsigned short* __restrict__ Wl,
                                               const float* __restrict__ dis,
                                               unsigned short* __restrict__ Hb, int n) {
  __shared__ unsigned short xs[64 * 136];
  const int t = threadIdx.x;
  const int w = t >> 6, l = t & 63;
  const int lr = l & 15, lk = (l >> 4) * 8;
  const int row0 = blockIdx.x * 64;

  bf16x8 Bh[2][4], Bl[2][4];
#pragma unroll
  for (int c2 = 0; c2 < 2; ++c2)
#pragma unroll
    for (int kb = 0; kb < 4; ++kb) {
      int colw = w * 32 + c2 * 16 + lr;
      Bh[c2][kb] = *(const bf16x8*)&Wh[(size_t)colw * 128 + kb * 32 + lk];
      Bl[c2][kb] = *(const bf16x8*)&Wl[(size_t)colw * 128 + kb * 32 + lk];
    }

  for (int i = t; i < 64 * 32; i += 256) {
    int r = i >> 5, q = i & 31;
    float4 v = make_float4(0.f, 0.f, 0.f, 0.f);
    if (row0 + r < n) v = ((const float4*)(X + (size_t)(row0 + r) * IN_C))[q];
    unsigned p0 = f2bf(v.x) | (f2bf(v.y) << 16);
    unsigned p1 = f2bf(v.z) | (f2bf(v.w) << 16);
    *(uint2*)&xs[r * 136 + q * 4] = make_uint2(p0, p1);
  }
  __syncthreads();

#pragma unroll
  for (int rst = 0; rst < 4; ++rst) {
    bf16x8 a[4];
#pragma unroll
    for (int kb = 0; kb < 4; ++kb)
      a[kb] = *(const bf16x8*)&xs[(rst * 16 + lr) * 136 + kb * 32 + lk];
    f32x4 acc0 = (f32x4){0.f, 0.f, 0.f, 0.f};
    f32x4 acc1 = (f32x4){0.f, 0.f, 0.f, 0.f};
#pragma unroll
    for (int kb = 0; kb < 4; ++kb) {
      acc0 = __builtin_amdgcn_mfma_f32_16x16x32_bf16(a[kb], Bh[0][kb], acc0, 0, 0, 0);
      acc1 = __builtin_amdgcn_mfma_f32_16x16x32_bf16(a[kb], Bh[1][kb], acc1, 0, 0, 0);
      acc0 = __builtin_amdgcn_mfma_f32_16x16x32_bf16(a[kb], Bl[0][kb], acc0, 0, 0, 0);
      acc1 = __builtin_amdgcn_mfma_f32_16x16x32_bf16(a[kb], Bl[1][kb], acc1, 0, 0, 0);
    }
    const int rbase = row0 + rst * 16 + (l >> 4) * 4;
    float dv[4];
#pragma unroll
    for (int j = 0; j < 4; ++j) dv[j] = (rbase + j < n) ? dis[rbase + j] : 0.f;
#pragma unroll
    for (int c2 = 0; c2 < 2; ++c2) {
      const int grp = w * 2 + c2;  // channel group (colw>>4), lr = within-group slot
      const f32x4& acc = c2 ? acc1 : acc0;
#pragma unroll
      for (int j = 0; j < 4; ++j) {
        int row = rbase + j;
        if (row < n)
          Hb[((size_t)grp * n + row) * 16 + lr] = (unsigned short)f2bf(acc[j] * dv[j]);
      }
    }
  }
}

// ---------------- MFMA GEMM layer 2: Hb[group][node][8ch] = bf16((G@W2)*dis) ----------------

__global__ __launch_bounds__(256) void k_mfma2(const unsigned* __restrict__ G,
                                               const unsigned short* __restrict__ Wh,
                                               const unsigned short* __restrict__ Wl,
                                               const float* __restrict__ dis,
                                               unsigned short* __restrict__ Hb, int n) {
  __shared__ unsigned short xs[64 * 136];
  const int t = threadIdx.x;
  const int w = t >> 6, l = t & 63;
  const int lr = l & 15, lk = (l >> 4) * 8;
  const int row0 = blockIdx.x * 64;

  bf16x8 Bh[4], Bl[4];
#pragma unroll
  for (int kb = 0; kb < 4; ++kb) {
    int colw = w * 16 + lr;
    Bh[kb] = *(const bf16x8*)&Wh[(size_t)colw * 128 + kb * 32 + lk];
    Bl[kb] = *(const bf16x8*)&Wl[(size_t)colw * 128 + kb * 32 + lk];
  }

  for (int i = t; i < 64 * 32; i += 256) {
    int r = i >> 5, q = i & 31;
    uint2 v = make_uint2(0u, 0u);
    if (row0 + r < n) v = *(const uint2*)&G[(size_t)(row0 + r) * 64 + q * 2];
    *(uint2*)&xs[r * 136 + q * 4] = v;
  }
  __syncthreads();

#pragma unroll
  for (int rst = 0; rst < 4; ++rst) {
    bf16x8 a[4];
#pragma unroll
    for (int kb = 0; kb < 4; ++kb)
      a[kb] = *(const bf16x8*)&xs[(rst * 16 + lr) * 136 + kb * 32 + lk];
    f32x4 acc = (f32x4){0.f, 0.f, 0.f, 0.f};
#pragma unroll
    for (int kb = 0; kb < 4; ++kb) {
      acc = __builtin_amdgcn_mfma_f32_16x16x32_bf16(a[kb], Bh[kb], acc, 0, 0, 0);
      acc = __builtin_amdgcn_mfma_f32_16x16x32_bf16(a[kb], Bl[kb], acc, 0, 0, 0);
    }
    const int rbase = row0 + rst * 16 + (l >> 4) * 4;
    const int colw = w * 16 + lr;
    const int grp = colw >> 3;       // channel group (8 ch each)
    const int within = colw & 7;
#pragma unroll
    for (int j = 0; j < 4; ++j) {
      int row = rbase + j;
      if (row < n)
        Hb[((size_t)grp * n + row) * 8 + within] =
            (unsigned short)f2bf(acc[j] * dis[row]);
    }
  }
}

// ---------------- aggregation: XCD-sharded channel groups ----------------
// grid = nodeblocks*8; g = blockIdx%8 pins channel-group to one XCD's L2.
// Layer 1: group = 16 ch (slice 3.2 MB); 8 edge-slots x 8 lanes per wave, 1 node/wave.

__global__ __launch_bounds__(256) void k_agg128(const unsigned* __restrict__ Hb,
                                                const int* __restrict__ rowptr,
                                                const int* __restrict__ col,
                                                const float* __restrict__ dis,
                                                const float* __restrict__ bias,
                                                unsigned* __restrict__ G, int n) {
  const int g = blockIdx.x & 7;
  const int nb = blockIdx.x >> 3;
  const int t = threadIdx.x;
  const int w = t >> 6, l = t & 63;
  const int slot = l >> 3, q = l & 7;
  const unsigned* T = Hb + (size_t)g * n * 8;  // uint view: 8 uints/node
  const float2 bq = *(const float2*)&bias[g * 16 + q * 2];

  for (int i = 0; i < 16; ++i) {
    const int node = nb * 64 + w * 16 + i;
    if (node >= n) return;
    const int beg = rowptr[node], end = rowptr[node + 1];
    float a0 = 0.f, a1 = 0.f;
    int j0 = beg;
    for (; j0 + 16 <= end; j0 += 16) {  // 2x8 edges, unconditional
      int s0 = __builtin_nontemporal_load(&col[j0 + slot]);
      int s1 = __builtin_nontemporal_load(&col[j0 + 8 + slot]);
      unsigned u0 = T[(size_t)s0 * 8 + q];
      unsigned u1 = T[(size_t)s1 * 8 + q];
      a0 += bflo(u0) + bflo(u1);
      a1 += bfhi(u0) + bfhi(u1);
    }
    for (; j0 < end; j0 += 8) {  // guarded tail
      int jj = j0 + slot;
      if (jj < end) {
        int s = __builtin_nontemporal_load(&col[jj]);
        unsigned u = T[(size_t)s * 8 + q];
        a0 += bflo(u);
        a1 += bfhi(u);
      }
    }
    a0 += __shfl_xor(a0, 8, 64); a0 += __shfl_xor(a0, 16, 64); a0 += __shfl_xor(a0, 32, 64);
    a1 += __shfl_xor(a1, 8, 64); a1 += __shfl_xor(a1, 16, 64); a1 += __shfl_xor(a1, 32, 64);
    const float di = dis[node];
    if (slot == 0) {
      unsigned su = T[(size_t)node * 8 + q];
      float r0 = fmaxf(fmaf(a0 + bflo(su), di, bq.x), 0.f);
      float r1 = fmaxf(fmaf(a1 + bfhi(su), di, bq.y), 0.f);
      G[(size_t)node * 64 + g * 8 + q] = f2bf(r0) | (f2bf(r1) << 16);
    }
  }
}

// Layer 2: group = 8 ch (slice 1.6 MB); 16 edge-slots x 4 lanes per wave.
__global__ __launch_bounds__(256) void k_agg64(const unsigned* __restrict__ Hb,
                                               const int* __restrict__ rowptr,
                                               const int* __restrict__ col,
                                               const float* __restrict__ dis,
                                               const float* __restrict__ bias,
                                               float* __restrict__ out, int n) {
  const int g = blockIdx.x & 7;
  const int nb = blockIdx.x >> 3;
  const int t = threadIdx.x;
  const int w = t >> 6, l = t & 63;
  const int slot = l >> 2, q = l & 3;
  const unsigned* T = Hb + (size_t)g * n * 4;  // uint view: 4 uints/node
  const float2 bq = *(const float2*)&bias[g * 8 + q * 2];

  for (int i = 0; i < 16; ++i) {
    const int node = nb * 64 + w * 16 + i;
    if (node >= n) return;
    const int beg = rowptr[node], end = rowptr[node + 1];
    float a0 = 0.f, a1 = 0.f;
    int j0 = beg;
    for (; j0 + 16 <= end; j0 += 16) {  // 16 edges, unconditional
      int s = __builtin_nontemporal_load(&col[j0 + slot]);
      unsigned u = T[(size_t)s * 4 + q];
      a0 += bflo(u);
      a1 += bfhi(u);
    }
    if (j0 < end) {  // guarded tail (single pass: end-j0 < 16)
      int jj = j0 + slot;
      if (jj < end) {
        int s = __builtin_nontemporal_load(&col[jj]);
        unsigned u = T[(size_t)s * 4 + q];
        a0 += bflo(u);
        a1 += bfhi(u);
      }
    }
    a0 += __shfl_xor(a0, 4, 64); a0 += __shfl_xor(a0, 8, 64);
    a0 += __shfl_xor(a0, 16, 64); a0 += __shfl_xor(a0, 32, 64);
    a1 += __shfl_xor(a1, 4, 64); a1 += __shfl_xor(a1, 8, 64);
    a1 += __shfl_xor(a1, 16, 64); a1 += __shfl_xor(a1, 32, 64);
    const float di = dis[node];
    if (slot == 0) {
      unsigned su = T[(size_t)node * 4 + q];
      float r0 = fmaf(a0 + bflo(su), di, bq.x);
      float r1 = fmaf(a1 + bfhi(su), di, bq.y);
      *(float2*)&out[(size_t)node * 64 + g * 8 + q * 2] = make_float2(r0, r1);
    }
  }
}

// ---------------- launch ----------------

extern "C" void kernel_launch(void* const* d_in, const int* in_sizes, int n_in,
                              void* d_out, int out_size, void* d_ws, size_t ws_size,
                              hipStream_t stream) {
  const float* x  = (const float*)d_in[0];
  const int*   ei = (const int*)d_in[1];
  const float* W1 = (const float*)d_in[2];
  const float* b1 = (const float*)d_in[3];
  const float* W2 = (const float*)d_in[4];
  const float* b2 = (const float*)d_in[5];
  float* out = (float*)d_out;

  const int N = N_NODES, E = N_EDGES;
  const int* esrc = ei;
  const int* edst = ei + E;

  char* w = (char*)d_ws;
  auto alloc = [&](size_t bytes) -> char* {
    char* p = w;
    w += (bytes + 255) & ~(size_t)255;
    return p;
  };
  float* dis          = (float*)alloc((size_t)N * 4);
  int* rowptr         = (int*)alloc((size_t)(N + 1) * 4);
  int* bcnt           = (int*)alloc((size_t)NBKT * 4);
  int* bsums          = (int*)alloc(512 * 4);
  int* col            = (int*)alloc((size_t)E * 4);
  unsigned* tmp       = (unsigned*)alloc((size_t)NBKT * CAP * 4);       // 7.2 MB
  unsigned short* h1b = (unsigned short*)alloc((size_t)8 * N * 16 * 2); // 25.6 MB blocked
  unsigned* g1        = (unsigned*)alloc((size_t)N * (HID_C / 2) * 4);  // 25.6 MB bf16x2
  unsigned short* h2b = (unsigned short*)alloc((size_t)8 * N * 8 * 2);  // 12.8 MB blocked
  unsigned short* W1h = (unsigned short*)alloc((size_t)IN_C * HID_C * 2);
  unsigned short* W1l = (unsigned short*)alloc((size_t)IN_C * HID_C * 2);
  unsigned short* W2h = (unsigned short*)alloc((size_t)HID_C * OUT_C * 2);
  unsigned short* W2l = (unsigned short*)alloc((size_t)HID_C * OUT_C * 2);

  // CSR build
  hipMemsetAsync(bcnt, 0, (size_t)NBKT * 4, stream);
  k_partA<<<(E + EPB - 1) / EPB, 256, 0, stream>>>(esrc, edst, bcnt, tmp, E);
  k_cnt_scan<<<NBKT, 256, 0, stream>>>(tmp, bcnt, rowptr, bsums, dis, N);
  k_scan_sums<<<1, 512, 0, stream>>>(bsums, NBKT);
  k_add_off<<<(N + 1 + 255) / 256, 256, 0, stream>>>(rowptr, bsums, N, E);
  k_partB<<<NBKT, 512, 0, stream>>>(tmp, bcnt, rowptr, col, N);
  k_prepW<<<(IN_C * HID_C + HID_C * OUT_C + 255) / 256, 256, 0, stream>>>(
      W1, W2, W1h, W1l, W2h, W2l);

  const int aggGrid = ((N + 63) / 64) * 8;  // nodeblocks x 8 channel-groups

  // layer 1
  k_mfma1<<<(N + 63) / 64, 256, 0, stream>>>(x, W1h, W1l, dis, h1b, N);
  k_agg128<<<aggGrid, 256, 0, stream>>>((const unsigned*)h1b, rowptr, col, dis, b1, g1, N);
  // layer 2
  k_mfma2<<<(N + 63) / 64, 256, 0, stream>>>(g1, W2h, W2l, dis, h2b, N);
  k_agg64<<<aggGrid, 256, 0, stream>>>((const unsigned*)h2b, rowptr, col, dis, b2, out, N);
}

// Round 10
// 209.984 us; speedup vs baseline: 3.1056x; 3.1056x over previous
//
#include <hip/hip_runtime.h>

#define N_NODES 100000
#define N_EDGES 1600000
#define IN_C 128
#define HID_C 128
#define OUT_C 64

#define SH 8                 // bucket = dst >> 8 (256 nodes/bucket)
#define NBKT 391             // ceil(100000/256)
#define CAP 4608             // bucket capacity: mean 4096 + 8 sigma
#define EPB 2048             // edges per block in phase A (782 blocks: grid-occupancy)
#define EPT 8                // EPB / 256

typedef __attribute__((ext_vector_type(8))) short bf16x8;
typedef __attribute__((ext_vector_type(4))) float f32x4;

// ---- bf16 helpers ----
static __device__ __forceinline__ unsigned f2bf(float f) {
  union { float f; unsigned u; } v; v.f = f;
  unsigned r = v.u + 0x7fffu + ((v.u >> 16) & 1u);
  return r >> 16;
}
static __device__ __forceinline__ float bf2f(unsigned hu) {
  union { unsigned u; float f; } v; v.u = hu << 16; return v.f;
}
static __device__ __forceinline__ float bflo(unsigned u) {
  union { unsigned u; float f; } v; v.u = u << 16; return v.f;
}
static __device__ __forceinline__ float bfhi(unsigned u) {
  union { unsigned u; float f; } v; v.u = u & 0xffff0000u; return v.f;
}

// ---------------- phase A: LDS-reorder radix partition by dst-bucket ----------------

__global__ __launch_bounds__(256) void k_partA(const int* __restrict__ src,
                                               const int* __restrict__ dst,
                                               int* __restrict__ bcnt,
                                               unsigned* __restrict__ tmp, int e) {
  __shared__ unsigned stage[EPB];        // 8 KB
  __shared__ unsigned short bid[EPB];    // 4 KB
  __shared__ int hist[NBKT];
  __shared__ int lstart[NBKT];
  __shared__ int base[NBKT];
  __shared__ int ps[256];
  const int t = threadIdx.x;
  const int e0 = blockIdx.x * EPB;
  const int m = (e0 + EPB < e ? EPB : e - e0);

  for (int i = t; i < NBKT; i += 256) hist[i] = 0;
  __syncthreads();

  int rsrc[EPT], rdst[EPT];
#pragma unroll
  for (int i = 0; i < EPT; ++i) {
    int idx = e0 + i * 256 + t;
    if (idx < e) {
      rsrc[i] = src[idx];
      rdst[i] = dst[idx];
      atomicAdd(&hist[rdst[i] >> SH], 1);
    }
  }
  __syncthreads();

  int a0 = (2 * t < NBKT) ? hist[2 * t] : 0;
  int a1 = (2 * t + 1 < NBKT) ? hist[2 * t + 1] : 0;
  ps[t] = a0 + a1;
  __syncthreads();
  for (int off = 1; off < 256; off <<= 1) {
    int add = (t >= off) ? ps[t - off] : 0;
    __syncthreads();
    ps[t] += add;
    __syncthreads();
  }
  int ex = ps[t] - (a0 + a1);
  if (2 * t < NBKT) lstart[2 * t] = ex;
  if (2 * t + 1 < NBKT) lstart[2 * t + 1] = ex + a0;

  for (int i = t; i < NBKT; i += 256) {
    int h = hist[i];
    base[i] = h ? atomicAdd(&bcnt[i], h) : 0;
    hist[i] = 0;
  }
  __syncthreads();

#pragma unroll
  for (int i = 0; i < EPT; ++i) {
    int idx = e0 + i * 256 + t;
    if (idx < e) {
      int d = rdst[i];
      int b = d >> SH;
      int pos = lstart[b] + atomicAdd(&hist[b], 1);
      stage[pos] = (unsigned)rsrc[i] | ((unsigned)(d & 255) << 17);
      bid[pos] = (unsigned short)b;
    }
  }
  __syncthreads();

  for (int pos = t; pos < m; pos += 256) {
    int b = bid[pos];
    int slot = base[b] + (pos - lstart[b]);
    if (slot < CAP)  // 8-sigma safety clamp
      tmp[(size_t)b * CAP + slot] = stage[pos];
  }
}

// single-block exclusive scan of clamped bcnt -> bstart[0..NBKT]
__global__ __launch_bounds__(512) void k_bscan(const int* __restrict__ bcnt,
                                               int* __restrict__ bstart) {
  __shared__ int s[512];
  const int t = threadIdx.x;
  int v = 0;
  if (t < NBKT) {
    v = bcnt[t];
    if (v > CAP) v = CAP;
  }
  s[t] = v;
  __syncthreads();
  for (int off = 1; off < 512; off <<= 1) {
    int add = (t >= off) ? s[t - off] : 0;
    __syncthreads();
    s[t] += add;
    __syncthreads();
  }
  if (t <= NBKT) bstart[t] = s[t] - v;  // t==NBKT (v=0) gets the total
}

// fused: per-bucket histogram -> dis + rowptr (bstart + local prefix) -> col scatter
__global__ __launch_bounds__(256) void k_bucket(const unsigned* __restrict__ tmp,
                                                const int* __restrict__ bcnt,
                                                const int* __restrict__ bstart,
                                                int* __restrict__ rowptr,
                                                int* __restrict__ col,
                                                float* __restrict__ dis, int n) {
  __shared__ int h[256];
  __shared__ int s[256];
  const int b = blockIdx.x, t = threadIdx.x;
  h[t] = 0;
  __syncthreads();
  int m = bcnt[b];
  if (m > CAP) m = CAP;
  const unsigned* tb = tmp + (size_t)b * CAP;
  for (int j = t; j < m; j += 256)
    atomicAdd(&h[tb[j] >> 17], 1);
  __syncthreads();
  const int node = (b << SH) + t;
  const int v = h[t];
  if (node < n) dis[node] = rsqrtf((float)(v + 1));
  s[t] = v;
  __syncthreads();
  for (int off = 1; off < 256; off <<= 1) {
    int add = (t >= off) ? s[t - off] : 0;
    __syncthreads();
    s[t] += add;
    __syncthreads();
  }
  const int base = bstart[b];
  const int ex = s[t] - v;
  if (node < n) rowptr[node] = base + ex;
  if (b == 0 && t == 0) rowptr[n] = bstart[NBKT];
  __syncthreads();
  h[t] = base + ex;  // reuse h as scatter cursor
  __syncthreads();
  for (int j = t; j < m; j += 256) {
    unsigned u = tb[j];
    int pos = atomicAdd(&h[u >> 17], 1);
    col[pos] = (int)(u & 0x1FFFFu);
  }
}

// ---------------- weight prep: transpose + split-bf16 (W = hi + lo) ----------------

__global__ void k_prepW(const float* __restrict__ W1, const float* __restrict__ W2,
                        unsigned short* __restrict__ W1h, unsigned short* __restrict__ W1l,
                        unsigned short* __restrict__ W2h, unsigned short* __restrict__ W2l) {
  int i = blockIdx.x * blockDim.x + threadIdx.x;
  if (i < IN_C * HID_C) {
    int k = i >> 7, c = i & 127;
    float w = W1[i];
    unsigned hi = f2bf(w);
    W1h[c * 128 + k] = (unsigned short)hi;
    W1l[c * 128 + k] = (unsigned short)f2bf(w - bf2f(hi));
  }
  int j = i - IN_C * HID_C;
  if (j >= 0 && j < HID_C * OUT_C) {
    int k = j >> 6, c = j & 63;
    float w = W2[j];
    unsigned hi = f2bf(w);
    W2h[c * 128 + k] = (unsigned short)hi;
    W2l[c * 128 + k] = (unsigned short)f2bf(w - bf2f(hi));
  }
}

// ---------------- MFMA GEMM layer 1 (weights register-resident) ----------------

__global__ __launch_bounds__(256) void k_mfma1(const float* __restrict__ X,
                                               const unsigned short* __restrict__ Wh,
                                               const unsigned short* __restrict__ Wl,
                                               const float* __restrict__ dis,
                                               unsigned short* __restrict__ Hs, int n) {
  __shared__ unsigned short xs[64 * 136];
  const int t = threadIdx.x;
  const int w = t >> 6, l = t & 63;
  const int lr = l & 15, lk = (l >> 4) * 8;
  const int row0 = blockIdx.x * 64;

  bf16x8 Bh[2][4], Bl[2][4];
#pragma unroll
  for (int c2 = 0; c2 < 2; ++c2)
#pragma unroll
    for (int kb = 0; kb < 4; ++kb) {
      int colw = w * 32 + c2 * 16 + lr;
      Bh[c2][kb] = *(const bf16x8*)&Wh[(size_t)colw * 128 + kb * 32 + lk];
      Bl[c2][kb] = *(const bf16x8*)&Wl[(size_t)colw * 128 + kb * 32 + lk];
    }

  for (int i = t; i < 64 * 32; i += 256) {
    int r = i >> 5, q = i & 31;
    float4 v = make_float4(0.f, 0.f, 0.f, 0.f);
    if (row0 + r < n) v = ((const float4*)(X + (size_t)(row0 + r) * IN_C))[q];
    unsigned p0 = f2bf(v.x) | (f2bf(v.y) << 16);
    unsigned p1 = f2bf(v.z) | (f2bf(v.w) << 16);
    *(uint2*)&xs[r * 136 + q * 4] = make_uint2(p0, p1);
  }
  __syncthreads();

#pragma unroll
  for (int rst = 0; rst < 4; ++rst) {
    bf16x8 a[4];
#pragma unroll
    for (int kb = 0; kb < 4; ++kb)
      a[kb] = *(const bf16x8*)&xs[(rst * 16 + lr) * 136 + kb * 32 + lk];
    f32x4 acc0 = (f32x4){0.f, 0.f, 0.f, 0.f};
    f32x4 acc1 = (f32x4){0.f, 0.f, 0.f, 0.f};
#pragma unroll
    for (int kb = 0; kb < 4; ++kb) {
      acc0 = __builtin_amdgcn_mfma_f32_16x16x32_bf16(a[kb], Bh[0][kb], acc0, 0, 0, 0);
      acc1 = __builtin_amdgcn_mfma_f32_16x16x32_bf16(a[kb], Bh[1][kb], acc1, 0, 0, 0);
      acc0 = __builtin_amdgcn_mfma_f32_16x16x32_bf16(a[kb], Bl[0][kb], acc0, 0, 0, 0);
      acc1 = __builtin_amdgcn_mfma_f32_16x16x32_bf16(a[kb], Bl[1][kb], acc1, 0, 0, 0);
    }
    const int rbase = row0 + rst * 16 + (l >> 4) * 4;
    float dv[4];
#pragma unroll
    for (int j = 0; j < 4; ++j) dv[j] = (rbase + j < n) ? dis[rbase + j] : 0.f;
#pragma unroll
    for (int c2 = 0; c2 < 2; ++c2) {
      int colw = w * 32 + c2 * 16 + lr;
      const f32x4& acc = c2 ? acc1 : acc0;
#pragma unroll
      for (int j = 0; j < 4; ++j) {
        int row = rbase + j;
        if (row < n) Hs[(size_t)row * HID_C + colw] = (unsigned short)f2bf(acc[j] * dv[j]);
      }
    }
  }
}

// ---------------- MFMA GEMM layer 2 (weights register-resident) ----------------

__global__ __launch_bounds__(256) void k_mfma2(const unsigned* __restrict__ G,
                                               const unsigned short* __restrict__ Wh,
                                               const unsigned short* __restrict__ Wl,
                                               const float* __restrict__ dis,
                                               unsigned short* __restrict__ Hs, int n) {
  __shared__ unsigned short xs[64 * 136];
  const int t = threadIdx.x;
  const int w = t >> 6, l = t & 63;
  const int lr = l & 15, lk = (l >> 4) * 8;
  const int row0 = blockIdx.x * 64;

  bf16x8 Bh[4], Bl[4];
#pragma unroll
  for (int kb = 0; kb < 4; ++kb) {
    int colw = w * 16 + lr;
    Bh[kb] = *(const bf16x8*)&Wh[(size_t)colw * 128 + kb * 32 + lk];
    Bl[kb] = *(const bf16x8*)&Wl[(size_t)colw * 128 + kb * 32 + lk];
  }

  for (int i = t; i < 64 * 32; i += 256) {
    int r = i >> 5, q = i & 31;
    uint2 v = make_uint2(0u, 0u);
    if (row0 + r < n) v = *(const uint2*)&G[(size_t)(row0 + r) * 64 + q * 2];
    *(uint2*)&xs[r * 136 + q * 4] = v;
  }
  __syncthreads();

#pragma unroll
  for (int rst = 0; rst < 4; ++rst) {
    bf16x8 a[4];
#pragma unroll
    for (int kb = 0; kb < 4; ++kb)
      a[kb] = *(const bf16x8*)&xs[(rst * 16 + lr) * 136 + kb * 32 + lk];
    f32x4 acc = (f32x4){0.f, 0.f, 0.f, 0.f};
#pragma unroll
    for (int kb = 0; kb < 4; ++kb) {
      acc = __builtin_amdgcn_mfma_f32_16x16x32_bf16(a[kb], Bh[kb], acc, 0, 0, 0);
      acc = __builtin_amdgcn_mfma_f32_16x16x32_bf16(a[kb], Bl[kb], acc, 0, 0, 0);
    }
    const int rbase = row0 + rst * 16 + (l >> 4) * 4;
    const int colw = w * 16 + lr;
#pragma unroll
    for (int j = 0; j < 4; ++j) {
      int row = rbase + j;
      if (row < n) Hs[(size_t)row * OUT_C + colw] =
          (unsigned short)f2bf(acc[j] * dis[row]);
    }
  }
}

// ---------------- aggregation (R6 structure: best measured) ----------------
// out[i] = dis[i]*(h'[i] + sum h'[s]) + b  [, relu]

__global__ __launch_bounds__(256) void k_agg128(const unsigned* __restrict__ Hs,
                                                const int* __restrict__ rowptr,
                                                const int* __restrict__ col,
                                                const float* __restrict__ dis,
                                                const float* __restrict__ bias,
                                                unsigned* __restrict__ G, int n) {
  const int node = (blockIdx.x * blockDim.x + threadIdx.x) >> 6;
  const int lane = threadIdx.x & 63;
  if (node >= n) return;
  unsigned u = Hs[(size_t)node * 64 + lane];
  float a0 = bflo(u), a1 = bfhi(u);
  int j = rowptr[node];
  const int end = rowptr[node + 1];
  for (; j + 8 <= end; j += 8) {
    int s0 = col[j], s1 = col[j + 1], s2 = col[j + 2], s3 = col[j + 3];
    int s4 = col[j + 4], s5 = col[j + 5], s6 = col[j + 6], s7 = col[j + 7];
    unsigned u0 = Hs[(size_t)s0 * 64 + lane];
    unsigned u1 = Hs[(size_t)s1 * 64 + lane];
    unsigned u2 = Hs[(size_t)s2 * 64 + lane];
    unsigned u3 = Hs[(size_t)s3 * 64 + lane];
    unsigned u4 = Hs[(size_t)s4 * 64 + lane];
    unsigned u5 = Hs[(size_t)s5 * 64 + lane];
    unsigned u6 = Hs[(size_t)s6 * 64 + lane];
    unsigned u7 = Hs[(size_t)s7 * 64 + lane];
    a0 += ((bflo(u0) + bflo(u1)) + (bflo(u2) + bflo(u3))) +
          ((bflo(u4) + bflo(u5)) + (bflo(u6) + bflo(u7)));
    a1 += ((bfhi(u0) + bfhi(u1)) + (bfhi(u2) + bfhi(u3))) +
          ((bfhi(u4) + bfhi(u5)) + (bfhi(u6) + bfhi(u7)));
  }
  for (; j + 4 <= end; j += 4) {
    int s0 = col[j], s1 = col[j + 1], s2 = col[j + 2], s3 = col[j + 3];
    unsigned u0 = Hs[(size_t)s0 * 64 + lane];
    unsigned u1 = Hs[(size_t)s1 * 64 + lane];
    unsigned u2 = Hs[(size_t)s2 * 64 + lane];
    unsigned u3 = Hs[(size_t)s3 * 64 + lane];
    a0 += (bflo(u0) + bflo(u1)) + (bflo(u2) + bflo(u3));
    a1 += (bfhi(u0) + bfhi(u1)) + (bfhi(u2) + bfhi(u3));
  }
  for (; j < end; ++j) {
    unsigned uu = Hs[(size_t)col[j] * 64 + lane];
    a0 += bflo(uu);
    a1 += bfhi(uu);
  }
  const float di = dis[node];
  const int c = lane * 2;
  float r0 = fmaxf(fmaf(a0, di, bias[c]), 0.f);
  float r1 = fmaxf(fmaf(a1, di, bias[c + 1]), 0.f);
  G[(size_t)node * 64 + lane] = f2bf(r0) | (f2bf(r1) << 16);
}

__global__ __launch_bounds__(256) void k_agg64(const unsigned* __restrict__ Hs,
                                               const int* __restrict__ rowptr,
                                               const int* __restrict__ col,
                                               const float* __restrict__ dis,
                                               const float* __restrict__ bias,
                                               float* __restrict__ out, int n) {
  const int node = (blockIdx.x * blockDim.x + threadIdx.x) >> 5;
  const int l = threadIdx.x & 31;
  if (node >= n) return;
  unsigned u = Hs[(size_t)node * 32 + l];
  float a0 = bflo(u), a1 = bfhi(u);
  int j = rowptr[node];
  const int end = rowptr[node + 1];
  for (; j + 8 <= end; j += 8) {
    int s0 = col[j], s1 = col[j + 1], s2 = col[j + 2], s3 = col[j + 3];
    int s4 = col[j + 4], s5 = col[j + 5], s6 = col[j + 6], s7 = col[j + 7];
    unsigned u0 = Hs[(size_t)s0 * 32 + l];
    unsigned u1 = Hs[(size_t)s1 * 32 + l];
    unsigned u2 = Hs[(size_t)s2 * 32 + l];
    unsigned u3 = Hs[(size_t)s3 * 32 + l];
    unsigned u4 = Hs[(size_t)s4 * 32 + l];
    unsigned u5 = Hs[(size_t)s5 * 32 + l];
    unsigned u6 = Hs[(size_t)s6 * 32 + l];
    unsigned u7 = Hs[(size_t)s7 * 32 + l];
    a0 += ((bflo(u0) + bflo(u1)) + (bflo(u2) + bflo(u3))) +
          ((bflo(u4) + bflo(u5)) + (bflo(u6) + bflo(u7)));
    a1 += ((bfhi(u0) + bfhi(u1)) + (bfhi(u2) + bfhi(u3))) +
          ((bfhi(u4) + bfhi(u5)) + (bfhi(u6) + bfhi(u7)));
  }
  for (; j + 4 <= end; j += 4) {
    int s0 = col[j], s1 = col[j + 1], s2 = col[j + 2], s3 = col[j + 3];
    unsigned u0 = Hs[(size_t)s0 * 32 + l];
    unsigned u1 = Hs[(size_t)s1 * 32 + l];
    unsigned u2 = Hs[(size_t)s2 * 32 + l];
    unsigned u3 = Hs[(size_t)s3 * 32 + l];
    a0 += (bflo(u0) + bflo(u1)) + (bflo(u2) + bflo(u3));
    a1 += (bfhi(u0) + bfhi(u1)) + (bfhi(u2) + bfhi(u3));
  }
  for (; j < end; ++j) {
    unsigned uu = Hs[(size_t)col[j] * 32 + l];
    a0 += bflo(uu);
    a1 += bfhi(uu);
  }
  const float di = dis[node];
  const int c = l * 2;
  float r0 = fmaf(a0, di, bias[c]);
  float r1 = fmaf(a1, di, bias[c + 1]);
  *(float2*)&out[(size_t)node * 64 + c] = make_float2(r0, r1);
}

// ---------------- launch ----------------

extern "C" void kernel_launch(void* const* d_in, const int* in_sizes, int n_in,
                              void* d_out, int out_size, void* d_ws, size_t ws_size,
                              hipStream_t stream) {
  const float* x  = (const float*)d_in[0];
  const int*   ei = (const int*)d_in[1];
  const float* W1 = (const float*)d_in[2];
  const float* b1 = (const float*)d_in[3];
  const float* W2 = (const float*)d_in[4];
  const float* b2 = (const float*)d_in[5];
  float* out = (float*)d_out;

  const int N = N_NODES, E = N_EDGES;
  const int* esrc = ei;
  const int* edst = ei + E;

  char* w = (char*)d_ws;
  auto alloc = [&](size_t bytes) -> char* {
    char* p = w;
    w += (bytes + 255) & ~(size_t)255;
    return p;
  };
  float* dis          = (float*)alloc((size_t)N * 4);
  int* rowptr         = (int*)alloc((size_t)(N + 1) * 4);
  int* bcnt           = (int*)alloc((size_t)NBKT * 4);
  int* bstart         = (int*)alloc((size_t)(NBKT + 1) * 4);
  int* col            = (int*)alloc((size_t)E * 4);
  unsigned* tmp       = (unsigned*)alloc((size_t)NBKT * CAP * 4);       // 7.2 MB
  unsigned short* h1s = (unsigned short*)alloc((size_t)N * HID_C * 2);  // 25.6 MB
  unsigned* g1        = (unsigned*)alloc((size_t)N * (HID_C / 2) * 4);  // 25.6 MB bf16x2
  unsigned short* h2s = (unsigned short*)alloc((size_t)N * OUT_C * 2);  // 12.8 MB
  unsigned short* W1h = (unsigned short*)alloc((size_t)IN_C * HID_C * 2);
  unsigned short* W1l = (unsigned short*)alloc((size_t)IN_C * HID_C * 2);
  unsigned short* W2h = (unsigned short*)alloc((size_t)HID_C * OUT_C * 2);
  unsigned short* W2l = (unsigned short*)alloc((size_t)HID_C * OUT_C * 2);

  // CSR build: partA -> bscan -> bucket (fused hist+scan+scatter)
  hipMemsetAsync(bcnt, 0, (size_t)NBKT * 4, stream);
  k_partA<<<(E + EPB - 1) / EPB, 256, 0, stream>>>(esrc, edst, bcnt, tmp, E);
  k_bscan<<<1, 512, 0, stream>>>(bcnt, bstart);
  k_bucket<<<NBKT, 256, 0, stream>>>(tmp, bcnt, bstart, rowptr, col, dis, N);
  k_prepW<<<(IN_C * HID_C + HID_C * OUT_C + 255) / 256, 256, 0, stream>>>(
      W1, W2, W1h, W1l, W2h, W2l);

  // layer 1
  k_mfma1<<<(N + 63) / 64, 256, 0, stream>>>(x, W1h, W1l, dis, h1s, N);
  k_agg128<<<(N * 64 + 255) / 256, 256, 0, stream>>>((const unsigned*)h1s, rowptr, col,
                                                     dis, b1, g1, N);
  // layer 2
  k_mfma2<<<(N + 63) / 64, 256, 0, stream>>>(g1, W2h, W2l, dis, h2s, N);
  k_agg64<<<(N * 32 + 255) / 256, 256, 0, stream>>>((const unsigned*)h2s, rowptr, col,
                                                    dis, b2, out, N);
}